// Round 10
// baseline (310.306 us; speedup 1.0000x reference)
//
#include <hip/hip_runtime.h>
#include <cstdint>
#include <cstddef>

typedef float f32x4 __attribute__((ext_vector_type(4)));
typedef short short8 __attribute__((ext_vector_type(8)));
typedef __bf16 bf16x8 __attribute__((ext_vector_type(8)));

__device__ __forceinline__ void mfma_bf16(f32x4& d, short8 a, short8 b){
  d = __builtin_amdgcn_mfma_f32_16x16x32_bf16(
        __builtin_bit_cast(bf16x8, a), __builtin_bit_cast(bf16x8, b), d, 0, 0, 0);
}

__device__ __forceinline__ unsigned short bf16_rn(float f){
  unsigned u = __float_as_uint(f);
  unsigned r = (u + 0x7FFF + ((u >> 16) & 1)) >> 16;
  return (unsigned short)r;
}

// 256-thread exclusive block scan (4 waves).
__device__ __forceinline__ int blockScan256Excl(int v, int* wsum){
  const int lane = threadIdx.x & 63, wv = threadIdx.x >> 6;
  int x = v;
  #pragma unroll
  for (int off = 1; off < 64; off <<= 1){
    int y = __shfl_up(x, off);
    if (lane >= off) x += y;
  }
  if (lane == 63) wsum[wv] = x;
  __syncthreads();
  int woff = 0;
  #pragma unroll
  for (int w = 0; w < 4; ++w) woff += (w < wv) ? wsum[w] : 0;
  return woff + x - v;
}

// ================= CSR build: two-level counting sort (no global atomics) =================
__global__ __launch_bounds__(256) void k_bcount(const int* __restrict__ dst, int E, int nb, int ntiles,
                                                int* __restrict__ blk_hist){
  __shared__ int h[256];
  const int tile = blockIdx.x;
  h[threadIdx.x] = 0;
  __syncthreads();
  const int base = tile * 2048;
  const int end = min(base + 2048, E);
  for (int i = base + threadIdx.x; i < end; i += 256)
    atomicAdd(&h[dst[i] >> 8], 1);
  __syncthreads();
  const int b = threadIdx.x;
  if (b < nb) blk_hist[(size_t)b * ntiles + tile] = h[b];
}

__global__ __launch_bounds__(256) void k_bscan(int* __restrict__ blk_hist, int nb, int ntiles,
                                               int* __restrict__ tot){
  __shared__ int wsum[4];
  __shared__ int carry;
  const int b = blockIdx.x;
  int* row = blk_hist + (size_t)b * ntiles;
  if (threadIdx.x == 0) carry = 0;
  __syncthreads();
  const int lane = threadIdx.x & 63, wv = threadIdx.x >> 6;
  for (int base = 0; base < ntiles; base += 256){
    const int i = base + threadIdx.x;
    const int v = (i < ntiles) ? row[i] : 0;
    int x = v;
    #pragma unroll
    for (int off = 1; off < 64; off <<= 1){
      int y = __shfl_up(x, off);
      if (lane >= off) x += y;
    }
    if (lane == 63) wsum[wv] = x;
    __syncthreads();
    int woff = 0;
    #pragma unroll
    for (int w = 0; w < 4; ++w) woff += (w < wv) ? wsum[w] : 0;
    const int incl = carry + woff + x;
    if (i < ntiles) row[i] = incl - v;
    __syncthreads();
    if (threadIdx.x == 255) carry = incl;
    __syncthreads();
  }
  if (threadIdx.x == 0) tot[b] = carry;
}

__global__ __launch_bounds__(256) void k_btot(const int* __restrict__ tot, int nb,
                                              int* __restrict__ bucket_base){
  __shared__ int wsum[4];
  const int t = threadIdx.x;
  const int v = (t < nb) ? tot[t] : 0;
  const int e = blockScan256Excl(v, wsum);
  if (t <= nb) bucket_base[t] = e;
}

__global__ __launch_bounds__(256) void k_bscat(const int* __restrict__ src, const int* __restrict__ dst,
                                               int E, int nb, int ntiles,
                                               const int* __restrict__ blk_off,
                                               const int* __restrict__ bucket_base,
                                               unsigned* __restrict__ ebuf){
  __shared__ int cnt[256];
  __shared__ int lofs[256];
  __shared__ int gbase[256];
  __shared__ unsigned sorted[2048];
  __shared__ unsigned char sb[2048];
  __shared__ int wsum[4];
  const int tile = blockIdx.x;
  cnt[threadIdx.x] = 0;
  __syncthreads();
  const int base = tile * 2048;
  const int end = min(base + 2048, E);
  const int m = end - base;

  int rank_[8]; int b_[8]; unsigned v_[8];
  #pragma unroll
  for (int k = 0; k < 8; ++k){
    const int j = threadIdx.x + k * 256;
    if (base + j < end){
      const int d = dst[base + j];
      const int s = src[base + j];
      const int b = d >> 8;
      b_[k] = b;
      v_[k] = ((unsigned)(d & 255) << 16) | (unsigned)s;
      rank_[k] = atomicAdd(&cnt[b], 1);
    } else b_[k] = -1;
  }
  __syncthreads();
  const int ex = blockScan256Excl(cnt[threadIdx.x], wsum);
  lofs[threadIdx.x] = ex;
  if (threadIdx.x < nb)
    gbase[threadIdx.x] = bucket_base[threadIdx.x] + blk_off[(size_t)threadIdx.x * ntiles + tile];
  __syncthreads();
  #pragma unroll
  for (int k = 0; k < 8; ++k){
    if (b_[k] >= 0){
      const int p = lofs[b_[k]] + rank_[k];
      sorted[p] = v_[k];
      sb[p] = (unsigned char)b_[k];
    }
  }
  __syncthreads();
  for (int j = threadIdx.x; j < m; j += 256){
    const int b = sb[j];
    ebuf[gbase[b] + (j - lofs[b])] = sorted[j];
  }
}

__global__ __launch_bounds__(256) void k_csrfin(const unsigned* __restrict__ ebuf,
                                                const int* __restrict__ bucket_base,
                                                int n, int E, int nb,
                                                int* __restrict__ row_ptr,
                                                float* __restrict__ inv,
                                                unsigned short* __restrict__ csr){
  __shared__ int hist[256], excl[256], cursor[256];
  __shared__ int wsum[4];
  __shared__ unsigned vals[8192];
  __shared__ unsigned short sorted[8192];
  const int b = blockIdx.x;
  const int ebase = bucket_base[b];
  const int ecnt = bucket_base[b + 1] - ebase;
  const int t = threadIdx.x;
  hist[t] = 0;
  __syncthreads();
  for (int j = t; j < ecnt; j += 256){
    const unsigned v = ebuf[ebase + j];
    vals[j] = v;
    atomicAdd(&hist[v >> 16], 1);
  }
  __syncthreads();
  const int ex = blockScan256Excl(hist[t], wsum);
  excl[t] = ex;
  cursor[t] = ex;
  const int node = b * 256 + t;
  if (node < n){
    row_ptr[node] = ebase + ex;
    const int c = hist[t];
    inv[node] = 1.0f / (float)(c > 0 ? c : 1);
  }
  if (b == nb - 1 && t == 0) row_ptr[n] = E;
  __syncthreads();
  for (int j = t; j < ecnt; j += 256){
    const unsigned v = vals[j];
    const int pos = atomicAdd(&cursor[v >> 16], 1);
    sorted[pos] = (unsigned short)(v & 0xFFFFu);
  }
  __syncthreads();
  for (int j = t; j < ecnt; j += 256)
    csr[ebase + j] = sorted[j];
}

// ---------------- fp32 -> bf16 SLICED table: slice[c][node][8 uints], c = col/16 ----------------
__global__ __launch_bounds__(256) void k_cvt(const float* __restrict__ in,
                                             unsigned* __restrict__ slice, int n){
  const int id = blockIdx.x * 256 + threadIdx.x;   // n*64 uints
  if (id >= n * 64) return;
  const int node = id >> 6, ui = id & 63;
  const float2 v = *(const float2*)&in[(size_t)id * 2];
  const unsigned packed = (unsigned)bf16_rn(v.x) | ((unsigned)bf16_rn(v.y) << 16);
  slice[((size_t)(ui >> 3) * n + node) * 8 + (ui & 7)] = packed;
}

// ---------------- column-tiled mean aggregation (XCD-bound slices) ----------------
// blockIdx%8 = column tile (16 cols, 32B/row, 1.6MB slice -> L2-resident per XCD)
// wave = 1 node: 8 neighbor-slots x 8 uint-slots; shfl_xor reduce; out row-major
__global__ __launch_bounds__(256) void k_aggt(const unsigned* __restrict__ slice,  // [8][n][8]
                                              const unsigned short* __restrict__ csr,
                                              const int* __restrict__ row_ptr,
                                              const float* __restrict__ inv_cnt,
                                              unsigned* __restrict__ outb,         // [n][64]
                                              int n){
  const int bid = blockIdx.x;
  const int ctile = bid & 7;
  const int node = (bid >> 3) * 4 + (threadIdx.x >> 6);
  if (node >= n) return;
  const int lane = threadIdx.x & 63;
  const int ns = lane >> 3;   // neighbor slot
  const int ls = lane & 7;    // uint slot
  const unsigned* __restrict__ tb = slice + (size_t)ctile * n * 8;
  const int beg = row_ptr[node], end = row_ptr[node + 1];
  float ax = 0.f, ay = 0.f;
  for (int j = beg + ns; j < end; j += 8){
    const unsigned u = tb[(size_t)csr[j] * 8 + ls];
    ax += __uint_as_float(u << 16);
    ay += __uint_as_float(u & 0xFFFF0000u);
  }
  ax += __shfl_xor(ax, 8);  ay += __shfl_xor(ay, 8);
  ax += __shfl_xor(ax, 16); ay += __shfl_xor(ay, 16);
  ax += __shfl_xor(ax, 32); ay += __shfl_xor(ay, 32);
  if (lane < 8){
    const float ic = inv_cnt[node];
    const unsigned packed = (unsigned)bf16_rn(ax * ic) | ((unsigned)bf16_rn(ay * ic) << 16);
    outb[(size_t)node * 64 + ctile * 8 + ls] = packed;
  }
}

// ---------------- weight pack + bf16 hi/lo split, FRAGMENT-MAJOR ----------------
__global__ void k_wcs(const float* __restrict__ wl, const float* __restrict__ wr,
                      short* __restrict__ bfr){
  int id = blockIdx.x * 256 + threadIdx.x;
  if (id >= 128 * 256) return;
  int c = id >> 8, k = id & 255;
  float w = (k < 128) ? wl[c * 128 + k] : wr[c * 128 + (k - 128)];
  unsigned short h = bf16_rn(w);
  float hf = __uint_as_float((unsigned)h << 16);
  unsigned short l = bf16_rn(w - hf);
  const int nt = c >> 4, mrow = c & 15;
  const int ks = k >> 5, kgrp = (k >> 3) & 3, j = k & 7;
  const int lane = kgrp * 16 + mrow;
  const size_t fbase = (size_t)((ks * 8 + nt) * 2) * 512 + lane * 8 + j;
  bfr[fbase] = (short)h;
  bfr[fbase + 512] = (short)l;
}

// ---------------- MFMA GEMM: prelu([A0|A1] @ W^T + b) ----------------
// A0 row-major uints [n][64] (agg out); A1 sliced uints [8][n][8].
// Layer1: write h1 sliced bf16. Layer2: fused head dot -> sbuf/pbuf (no h2 materialized).
__global__ __launch_bounds__(256) void k_gemm_mfma(const unsigned* __restrict__ A0u,
                                                   const unsigned* __restrict__ A1s,
                                                   const short* __restrict__ bfr,
                                                   const float* __restrict__ bias,
                                                   const float* __restrict__ alpha_p,
                                                   unsigned short* __restrict__ out16s, // sliced, or null
                                                   const float* __restrict__ uvec,      // u[257], or null
                                                   float* __restrict__ sbuf,
                                                   float* __restrict__ pbuf,
                                                   int n){
  __shared__ short aT[2][64 * 128];   // 2 tables x 64 rows x 256B, XOR-swizzled
  const int t = threadIdx.x;
  const int lane = t & 63;
  const int wv = t >> 6;
  const int nodeBase = blockIdx.x * 64;

  #pragma unroll
  for (int tab = 0; tab < 2; ++tab){
    #pragma unroll
    for (int it = 0; it < 4; ++it){
      const int chunk = it * 256 + t;
      const int row = chunk >> 4;
      const int slot = chunk & 15;
      int gr = nodeBase + row; if (gr > n - 1) gr = n - 1;
      const uint4 v = (tab == 0)
        ? *(const uint4*)&A0u[(size_t)gr * 64 + slot * 4]
        : *(const uint4*)&A1s[((size_t)(slot >> 1) * n + gr) * 8 + (slot & 1) * 4];
      const int sslot = slot ^ (row & 7);
      *(uint4*)((char*)&aT[tab][0] + row * 256 + sslot * 16) = v;
    }
  }
  __syncthreads();

  const short8* __restrict__ Bf = (const short8*)bfr;
  const int mrow = lane & 15;
  const int kgrp = lane >> 4;
  const int arow = wv * 16 + mrow;

  f32x4 acc[8];
  #pragma unroll
  for (int i = 0; i < 8; ++i) acc[i] = (f32x4){0.f, 0.f, 0.f, 0.f};

  #pragma unroll
  for (int ks = 0; ks < 8; ++ks){
    const int tab = ks >> 2;
    const int slot_r = (ks & 3) * 4 + kgrp;
    const short8 aF = *(const short8*)((const char*)&aT[tab][0] + arow * 256 + (slot_r ^ (arow & 7)) * 16);

    short8 bh[8], bl[8];
    const int fb = ks * 16;
    #pragma unroll
    for (int nt = 0; nt < 8; ++nt){
      bh[nt] = Bf[(size_t)(fb + nt * 2 + 0) * 64 + lane];
      bl[nt] = Bf[(size_t)(fb + nt * 2 + 1) * 64 + lane];
    }
    #pragma unroll
    for (int nt = 0; nt < 8; ++nt){
      mfma_bf16(acc[nt], aF, bh[nt]);
      mfma_bf16(acc[nt], aF, bl[nt]);
    }
  }

  const float alpha = *alpha_p;
  const int nodeQ = nodeBase + wv * 16 + kgrp * 4;

  if (out16s){
    // layer 1: sliced bf16 h1 write
    #pragma unroll
    for (int nt = 0; nt < 8; ++nt){
      const int col = nt * 16 + mrow;
      const float bv = bias[col];
      #pragma unroll
      for (int j = 0; j < 4; ++j){
        const int onode = nodeQ + j;
        if (onode < n){
          float v = acc[nt][j] + bv;
          v = fmaxf(v, 0.f) + alpha * fminf(v, 0.f);
          out16s[((size_t)nt * n + onode) * 16 + mrow] = bf16_rn(v);
        }
      }
    }
  } else {
    // layer 2: fused head dot: s = h2.u_l ; partial = h2.u_r + c
    float sdot[4] = {0,0,0,0}, tdot[4] = {0,0,0,0};
    #pragma unroll
    for (int nt = 0; nt < 8; ++nt){
      const int col = nt * 16 + mrow;
      const float bv = bias[col];
      const float ul = uvec[col];
      const float ur = uvec[128 + col];
      #pragma unroll
      for (int j = 0; j < 4; ++j){
        float v = acc[nt][j] + bv;
        v = fmaxf(v, 0.f) + alpha * fminf(v, 0.f);
        sdot[j] = fmaf(v, ul, sdot[j]);
        tdot[j] = fmaf(v, ur, tdot[j]);
      }
    }
    #pragma unroll
    for (int j = 0; j < 4; ++j){
      #pragma unroll
      for (int off = 1; off < 16; off <<= 1){
        sdot[j] += __shfl_xor(sdot[j], off);
        tdot[j] += __shfl_xor(tdot[j], off);
      }
    }
    if (mrow == 0){
      const float c = uvec[256];
      #pragma unroll
      for (int j = 0; j < 4; ++j){
        const int onode = nodeQ + j;
        if (onode < n){
          sbuf[onode] = sdot[j];
          pbuf[onode] = tdot[j] + c;
        }
      }
    }
  }
}

// ---------------- layer-3 fusion vector ----------------
__global__ void k_u(const float* __restrict__ w3l, const float* __restrict__ w3r,
                    const float* __restrict__ b3, const float* __restrict__ wp,
                    const float* __restrict__ bp, float* __restrict__ u){
  int k = threadIdx.x;
  float sl = 0.f, sr = 0.f;
  for (int o = 0; o < 64; ++o){
    float w = wp[o];
    sl = fmaf(w, w3l[o * 128 + k], sl);
    sr = fmaf(w, w3r[o * 128 + k], sr);
  }
  u[k] = sl; u[128 + k] = sr;
  if (k == 0){
    float c = bp[0];
    for (int o = 0; o < 64; ++o) c = fmaf(wp[o], b3[o], c);
    u[256] = c;
  }
}

__global__ __launch_bounds__(256) void k_final(const float* __restrict__ s, const float* __restrict__ partial,
                        const unsigned short* __restrict__ csr, const int* __restrict__ row_ptr,
                        const float* __restrict__ inv_cnt, float* __restrict__ out, int n){
  const int t = blockIdx.x * blockDim.x + threadIdx.x;
  const int node = t >> 2;
  const int sub = t & 3;
  if (node >= n) return;
  const int b = row_ptr[node], e = row_ptr[node + 1];
  float a0 = 0.f, a1 = 0.f;
  int j = b + sub;
  for (; j + 4 < e; j += 8){
    a0 += s[csr[j]];
    a1 += s[csr[j + 4]];
  }
  if (j < e) a0 += s[csr[j]];
  float acc = a0 + a1;
  acc += __shfl_down(acc, 1);
  acc += __shfl_down(acc, 2);
  if (sub == 0) out[node] = acc * inv_cnt[node] + partial[node];
}

// ---------------- launch ----------------
extern "C" void kernel_launch(void* const* d_in, const int* in_sizes, int n_in,
                              void* d_out, int out_size, void* d_ws, size_t ws_size,
                              hipStream_t stream){
  const float* x   = (const float*)d_in[0];
  const int*   ei  = (const int*)d_in[1];
  const float* w1l = (const float*)d_in[2];
  const float* w1r = (const float*)d_in[3];
  const float* b1  = (const float*)d_in[4];
  const float* w2l = (const float*)d_in[5];
  const float* w2r = (const float*)d_in[6];
  const float* b2  = (const float*)d_in[7];
  const float* w3l = (const float*)d_in[8];
  const float* w3r = (const float*)d_in[9];
  const float* b3  = (const float*)d_in[10];
  const float* ap  = (const float*)d_in[11];
  const float* wp  = (const float*)d_in[12];
  const float* bp  = (const float*)d_in[13];

  const int n = out_size;              // 50000 nodes
  const int E = in_sizes[1] / 2;       // 800000 edges
  const int* srcI = ei;
  const int* dstI = ei + E;

  const int ntiles = (E + 2047) / 2048;
  const int nb = (n + 255) >> 8;       // 196 buckets

  char* base = (char*)d_ws;
  size_t off = 0;
  auto take = [&](size_t bytes) -> char* {
    off = (off + 255) & ~(size_t)255;
    char* p = base + off;
    off += bytes;
    return p;
  };
  int*      blk_hist = (int*)   take((size_t)nb * ntiles * 4);
  int*      tot      = (int*)   take((size_t)nb * 4);
  int*      bbase    = (int*)   take(((size_t)nb + 1) * 4);
  unsigned* ebuf     = (unsigned*)take((size_t)E * 4);
  int*      rowp     = (int*)   take(((size_t)n + 1) * 4);
  float*    inv      = (float*) take((size_t)n * 4);
  unsigned short* csr = (unsigned short*)take((size_t)E * 2);
  unsigned* B1u = (unsigned*)take((size_t)n * 64 * 4);            // agg out, row-major uints
  unsigned* xbs = (unsigned*)take((size_t)n * 64 * 4);            // x bf16, sliced
  unsigned* h1s = (unsigned*)take((size_t)n * 64 * 4);            // h1 bf16, sliced
  float*    sbuf = (float*)take((size_t)n * 4);
  float*    pbuf = (float*)take((size_t)n * 4);
  float*    u    = (float*)take(257 * 4);
  short*    bfr  = (short*)take((size_t)128 * 512 * 2);
  (void)ws_size; (void)n_in;

  // CSR build: counting sort, no global atomics, coalesced writes
  k_bcount<<<ntiles, 256, 0, stream>>>(dstI, E, nb, ntiles, blk_hist);
  k_bscan <<<nb,     256, 0, stream>>>(blk_hist, nb, ntiles, tot);
  k_btot  <<<1,      256, 0, stream>>>(tot, nb, bbase);
  k_bscat <<<ntiles, 256, 0, stream>>>(srcI, dstI, E, nb, ntiles, blk_hist, bbase, ebuf);
  k_csrfin<<<nb,     256, 0, stream>>>(ebuf, bbase, n, E, nb, rowp, inv, csr);

  // sliced bf16 feature table
  k_cvt<<<(n * 64 + 255) / 256, 256, 0, stream>>>(x, xbs, n);

  const int aggGrid  = ((n + 3) / 4) * 8;    // x8 column tiles (XCD-bound)
  const int gemmGrid = (n + 63) / 64;

  // layer 1: h1 = prelu([agg(x)|x] @ W1 + b1)  -> sliced bf16
  k_aggt     <<<aggGrid, 256, 0, stream>>>(xbs, csr, rowp, inv, B1u, n);
  k_wcs      <<<128, 256, 0, stream>>>(w1l, w1r, bfr);
  k_gemm_mfma<<<gemmGrid, 256, 0, stream>>>(B1u, xbs, bfr, b1, ap, (unsigned short*)h1s,
                                            (const float*)nullptr, (float*)nullptr, (float*)nullptr, n);

  // layer 2: fused h2 GEMM + head dot -> sbuf/pbuf (h2 never materialized)
  k_u        <<<1, 128, 0, stream>>>(w3l, w3r, b3, wp, bp, u);
  k_aggt     <<<aggGrid, 256, 0, stream>>>(h1s, csr, rowp, inv, B1u, n);
  k_wcs      <<<128, 256, 0, stream>>>(w2l, w2r, bfr);
  k_gemm_mfma<<<gemmGrid, 256, 0, stream>>>(B1u, h1s, bfr, b2, ap, (unsigned short*)nullptr,
                                            u, sbuf, pbuf, n);

  // final: level = mean(s) + partial
  k_final<<<(n * 4 + 255) / 256, 256, 0, stream>>>(sbuf, pbuf, csr, rowp, inv, (float*)d_out, n);
}

// Round 11
// 163.581 us; speedup vs baseline: 1.8969x; 1.8969x over previous
//
#include <hip/hip_runtime.h>
#include <cstdint>
#include <cstddef>

typedef float f32x4 __attribute__((ext_vector_type(4)));
typedef short short8 __attribute__((ext_vector_type(8)));
typedef __bf16 bf16x8 __attribute__((ext_vector_type(8)));

__device__ __forceinline__ void mfma_bf16(f32x4& d, short8 a, short8 b){
  d = __builtin_amdgcn_mfma_f32_16x16x32_bf16(
        __builtin_bit_cast(bf16x8, a), __builtin_bit_cast(bf16x8, b), d, 0, 0, 0);
}

__device__ __forceinline__ unsigned short bf16_rn(float f){
  unsigned u = __float_as_uint(f);
  unsigned r = (u + 0x7FFF + ((u >> 16) & 1)) >> 16;
  return (unsigned short)r;
}

// 256-thread exclusive block scan (4 waves).
__device__ __forceinline__ int blockScan256Excl(int v, int* wsum){
  const int lane = threadIdx.x & 63, wv = threadIdx.x >> 6;
  int x = v;
  #pragma unroll
  for (int off = 1; off < 64; off <<= 1){
    int y = __shfl_up(x, off);
    if (lane >= off) x += y;
  }
  if (lane == 63) wsum[wv] = x;
  __syncthreads();
  int woff = 0;
  #pragma unroll
  for (int w = 0; w < 4; ++w) woff += (w < wv) ? wsum[w] : 0;
  return woff + x - v;
}

// ================= CSR build: two-level counting sort (no global atomics) =================
__global__ __launch_bounds__(256) void k_bcount(const int* __restrict__ dst, int E, int nb, int ntiles,
                                                int* __restrict__ blk_hist){
  __shared__ int h[256];
  const int tile = blockIdx.x;
  h[threadIdx.x] = 0;
  __syncthreads();
  const int base = tile * 2048;
  const int end = min(base + 2048, E);
  for (int i = base + threadIdx.x; i < end; i += 256)
    atomicAdd(&h[dst[i] >> 8], 1);
  __syncthreads();
  const int b = threadIdx.x;
  if (b < nb) blk_hist[(size_t)b * ntiles + tile] = h[b];
}

__global__ __launch_bounds__(256) void k_bscan(int* __restrict__ blk_hist, int nb, int ntiles,
                                               int* __restrict__ tot){
  __shared__ int wsum[4];
  __shared__ int carry;
  const int b = blockIdx.x;
  int* row = blk_hist + (size_t)b * ntiles;
  if (threadIdx.x == 0) carry = 0;
  __syncthreads();
  const int lane = threadIdx.x & 63, wv = threadIdx.x >> 6;
  for (int base = 0; base < ntiles; base += 256){
    const int i = base + threadIdx.x;
    const int v = (i < ntiles) ? row[i] : 0;
    int x = v;
    #pragma unroll
    for (int off = 1; off < 64; off <<= 1){
      int y = __shfl_up(x, off);
      if (lane >= off) x += y;
    }
    if (lane == 63) wsum[wv] = x;
    __syncthreads();
    int woff = 0;
    #pragma unroll
    for (int w = 0; w < 4; ++w) woff += (w < wv) ? wsum[w] : 0;
    const int incl = carry + woff + x;
    if (i < ntiles) row[i] = incl - v;
    __syncthreads();
    if (threadIdx.x == 255) carry = incl;
    __syncthreads();
  }
  if (threadIdx.x == 0) tot[b] = carry;
}

__global__ __launch_bounds__(256) void k_btot(const int* __restrict__ tot, int nb,
                                              int* __restrict__ bucket_base){
  __shared__ int wsum[4];
  const int t = threadIdx.x;
  const int v = (t < nb) ? tot[t] : 0;
  const int e = blockScan256Excl(v, wsum);
  if (t <= nb) bucket_base[t] = e;
}

__global__ __launch_bounds__(256) void k_bscat(const int* __restrict__ src, const int* __restrict__ dst,
                                               int E, int nb, int ntiles,
                                               const int* __restrict__ blk_off,
                                               const int* __restrict__ bucket_base,
                                               unsigned* __restrict__ ebuf){
  __shared__ int cnt[256];
  __shared__ int lofs[256];
  __shared__ int gbase[256];
  __shared__ unsigned sorted[2048];
  __shared__ unsigned char sb[2048];
  __shared__ int wsum[4];
  const int tile = blockIdx.x;
  cnt[threadIdx.x] = 0;
  __syncthreads();
  const int base = tile * 2048;
  const int end = min(base + 2048, E);
  const int m = end - base;

  int rank_[8]; int b_[8]; unsigned v_[8];
  #pragma unroll
  for (int k = 0; k < 8; ++k){
    const int j = threadIdx.x + k * 256;
    if (base + j < end){
      const int d = dst[base + j];
      const int s = src[base + j];
      const int b = d >> 8;
      b_[k] = b;
      v_[k] = ((unsigned)(d & 255) << 16) | (unsigned)s;
      rank_[k] = atomicAdd(&cnt[b], 1);
    } else b_[k] = -1;
  }
  __syncthreads();
  const int ex = blockScan256Excl(cnt[threadIdx.x], wsum);
  lofs[threadIdx.x] = ex;
  if (threadIdx.x < nb)
    gbase[threadIdx.x] = bucket_base[threadIdx.x] + blk_off[(size_t)threadIdx.x * ntiles + tile];
  __syncthreads();
  #pragma unroll
  for (int k = 0; k < 8; ++k){
    if (b_[k] >= 0){
      const int p = lofs[b_[k]] + rank_[k];
      sorted[p] = v_[k];
      sb[p] = (unsigned char)b_[k];
    }
  }
  __syncthreads();
  for (int j = threadIdx.x; j < m; j += 256){
    const int b = sb[j];
    ebuf[gbase[b] + (j - lofs[b])] = sorted[j];
  }
}

__global__ __launch_bounds__(256) void k_csrfin(const unsigned* __restrict__ ebuf,
                                                const int* __restrict__ bucket_base,
                                                int n, int E, int nb,
                                                int* __restrict__ row_ptr,
                                                float* __restrict__ inv,
                                                unsigned short* __restrict__ csr){
  __shared__ int hist[256], excl[256], cursor[256];
  __shared__ int wsum[4];
  __shared__ unsigned vals[8192];
  __shared__ unsigned short sorted[8192];
  const int b = blockIdx.x;
  const int ebase = bucket_base[b];
  const int ecnt = bucket_base[b + 1] - ebase;
  const int t = threadIdx.x;
  hist[t] = 0;
  __syncthreads();
  for (int j = t; j < ecnt; j += 256){
    const unsigned v = ebuf[ebase + j];
    vals[j] = v;
    atomicAdd(&hist[v >> 16], 1);
  }
  __syncthreads();
  const int ex = blockScan256Excl(hist[t], wsum);
  excl[t] = ex;
  cursor[t] = ex;
  const int node = b * 256 + t;
  if (node < n){
    row_ptr[node] = ebase + ex;
    const int c = hist[t];
    inv[node] = 1.0f / (float)(c > 0 ? c : 1);
  }
  if (b == nb - 1 && t == 0) row_ptr[n] = E;
  __syncthreads();
  for (int j = t; j < ecnt; j += 256){
    const unsigned v = vals[j];
    const int pos = atomicAdd(&cursor[v >> 16], 1);
    sorted[pos] = (unsigned short)(v & 0xFFFFu);
  }
  __syncthreads();
  for (int j = t; j < ecnt; j += 256)
    csr[ebase + j] = sorted[j];
}

// ---------------- fp32 -> bf16 table convert (row-major) ----------------
__global__ __launch_bounds__(256) void k_cvt(const float* __restrict__ in,
                                             unsigned short* __restrict__ out, int total){
  const int i = (blockIdx.x * 256 + threadIdx.x) * 4;
  if (i >= total) return;
  const float4 v = *(const float4*)&in[i];
  ushort2 a, b;
  a.x = bf16_rn(v.x); a.y = bf16_rn(v.y);
  b.x = bf16_rn(v.z); b.y = bf16_rn(v.w);
  *(ushort2*)&out[i] = a;
  *(ushort2*)&out[i + 2] = b;
}

// ---------------- mean aggregation: bf16 gather, fp32 accumulate, bf16 out ----------------
// one wave per node; lane covers cols {2*lane, 2*lane+1} = one uint (2 bf16) per row
__global__ __launch_bounds__(256) void k_aggb(const unsigned short* __restrict__ featb,
                                              const unsigned short* __restrict__ csr,
                                              const int* __restrict__ row_ptr,
                                              const float* __restrict__ inv_cnt,
                                              unsigned short* __restrict__ outb, int n){
  const int lane = threadIdx.x & 63;
  const int node = (blockIdx.x * blockDim.x + threadIdx.x) >> 6;
  if (node >= n) return;
  const int beg = row_ptr[node];
  const int end = row_ptr[node + 1];
  const unsigned* __restrict__ fb = (const unsigned*)featb;   // [node][64]

  float ax0=0.f, ay0=0.f, ax1=0.f, ay1=0.f, ax2=0.f, ay2=0.f, ax3=0.f, ay3=0.f;
  float ax4=0.f, ay4=0.f, ax5=0.f, ay5=0.f, ax6=0.f, ay6=0.f, ax7=0.f, ay7=0.f;

  int j = beg;
  for (; j + 8 <= end; j += 8){
    const int s0 = csr[j+0], s1 = csr[j+1], s2 = csr[j+2], s3 = csr[j+3];
    const int s4 = csr[j+4], s5 = csr[j+5], s6 = csr[j+6], s7 = csr[j+7];
    const unsigned u0 = fb[(size_t)s0 * 64 + lane];
    const unsigned u1 = fb[(size_t)s1 * 64 + lane];
    const unsigned u2 = fb[(size_t)s2 * 64 + lane];
    const unsigned u3 = fb[(size_t)s3 * 64 + lane];
    const unsigned u4 = fb[(size_t)s4 * 64 + lane];
    const unsigned u5 = fb[(size_t)s5 * 64 + lane];
    const unsigned u6 = fb[(size_t)s6 * 64 + lane];
    const unsigned u7 = fb[(size_t)s7 * 64 + lane];
    ax0 += __uint_as_float(u0 << 16); ay0 += __uint_as_float(u0 & 0xFFFF0000u);
    ax1 += __uint_as_float(u1 << 16); ay1 += __uint_as_float(u1 & 0xFFFF0000u);
    ax2 += __uint_as_float(u2 << 16); ay2 += __uint_as_float(u2 & 0xFFFF0000u);
    ax3 += __uint_as_float(u3 << 16); ay3 += __uint_as_float(u3 & 0xFFFF0000u);
    ax4 += __uint_as_float(u4 << 16); ay4 += __uint_as_float(u4 & 0xFFFF0000u);
    ax5 += __uint_as_float(u5 << 16); ay5 += __uint_as_float(u5 & 0xFFFF0000u);
    ax6 += __uint_as_float(u6 << 16); ay6 += __uint_as_float(u6 & 0xFFFF0000u);
    ax7 += __uint_as_float(u7 << 16); ay7 += __uint_as_float(u7 & 0xFFFF0000u);
  }
  if (j + 4 <= end){
    const int s0 = csr[j+0], s1 = csr[j+1], s2 = csr[j+2], s3 = csr[j+3];
    const unsigned u0 = fb[(size_t)s0 * 64 + lane];
    const unsigned u1 = fb[(size_t)s1 * 64 + lane];
    const unsigned u2 = fb[(size_t)s2 * 64 + lane];
    const unsigned u3 = fb[(size_t)s3 * 64 + lane];
    ax0 += __uint_as_float(u0 << 16); ay0 += __uint_as_float(u0 & 0xFFFF0000u);
    ax1 += __uint_as_float(u1 << 16); ay1 += __uint_as_float(u1 & 0xFFFF0000u);
    ax2 += __uint_as_float(u2 << 16); ay2 += __uint_as_float(u2 & 0xFFFF0000u);
    ax3 += __uint_as_float(u3 << 16); ay3 += __uint_as_float(u3 & 0xFFFF0000u);
    j += 4;
  }
  for (; j < end; ++j){
    const int s = csr[j];
    const unsigned u = fb[(size_t)s * 64 + lane];
    ax4 += __uint_as_float(u << 16); ay4 += __uint_as_float(u & 0xFFFF0000u);
  }

  const float ic = inv_cnt[node];
  const float ox = (((ax0 + ax1) + (ax2 + ax3)) + ((ax4 + ax5) + (ax6 + ax7))) * ic;
  const float oy = (((ay0 + ay1) + (ay2 + ay3)) + ((ay4 + ay5) + (ay6 + ay7))) * ic;
  const unsigned packed = (unsigned)bf16_rn(ox) | ((unsigned)bf16_rn(oy) << 16);
  ((unsigned*)outb)[(size_t)node * 64 + lane] = packed;
}

// ---------------- weight pack + bf16 hi/lo split, FRAGMENT-MAJOR ----------------
__global__ void k_wcs(const float* __restrict__ wl, const float* __restrict__ wr,
                      short* __restrict__ bfr){
  int id = blockIdx.x * 256 + threadIdx.x;
  if (id >= 128 * 256) return;
  int c = id >> 8, k = id & 255;
  float w = (k < 128) ? wl[c * 128 + k] : wr[c * 128 + (k - 128)];
  unsigned short h = bf16_rn(w);
  float hf = __uint_as_float((unsigned)h << 16);
  unsigned short l = bf16_rn(w - hf);
  const int nt = c >> 4, mrow = c & 15;
  const int ks = k >> 5, kgrp = (k >> 3) & 3, j = k & 7;
  const int lane = kgrp * 16 + mrow;
  const size_t fbase = (size_t)((ks * 8 + nt) * 2) * 512 + lane * 8 + j;
  bfr[fbase] = (short)h;
  bfr[fbase + 512] = (short)l;
}

// ---------------- MFMA GEMM: prelu([A0|A1] @ W^T + b) ----------------
// A0,A1 bf16 row-major [n][128]; A staged in LDS (XOR-swizzled); W split hi/lo.
// Layer1 (out16 != null): write h1 bf16 row-major.
// Layer2 (uvec != null): fused head dot -> sbuf/pbuf (h2 never materialized).
__global__ __launch_bounds__(256) void k_gemm_mfma(const unsigned short* __restrict__ A0b,
                                                   const unsigned short* __restrict__ A1b,
                                                   const short* __restrict__ bfr,
                                                   const float* __restrict__ bias,
                                                   const float* __restrict__ alpha_p,
                                                   unsigned short* __restrict__ out16,  // or null
                                                   const float* __restrict__ uvec,      // or null
                                                   float* __restrict__ sbuf,
                                                   float* __restrict__ pbuf,
                                                   int n){
  __shared__ short aT[2][64 * 128];   // 2 tables x 64 rows x 256B, XOR-swizzled
  const int t = threadIdx.x;
  const int lane = t & 63;
  const int wv = t >> 6;
  const int nodeBase = blockIdx.x * 64;

  #pragma unroll
  for (int tab = 0; tab < 2; ++tab){
    const unsigned short* __restrict__ src = tab ? A1b : A0b;
    #pragma unroll
    for (int it = 0; it < 4; ++it){
      const int chunk = it * 256 + t;
      const int row = chunk >> 4;
      const int slot = chunk & 15;
      int gr = nodeBase + row; if (gr > n - 1) gr = n - 1;
      const uint4 v = *(const uint4*)&src[(size_t)gr * 128 + slot * 8];
      const int sslot = slot ^ (row & 7);
      *(uint4*)((char*)&aT[tab][0] + row * 256 + sslot * 16) = v;
    }
  }
  __syncthreads();

  const short8* __restrict__ Bf = (const short8*)bfr;
  const int mrow = lane & 15;
  const int kgrp = lane >> 4;
  const int arow = wv * 16 + mrow;

  f32x4 acc[8];
  #pragma unroll
  for (int i = 0; i < 8; ++i) acc[i] = (f32x4){0.f, 0.f, 0.f, 0.f};

  #pragma unroll
  for (int ks = 0; ks < 8; ++ks){
    const int tab = ks >> 2;
    const int slot_r = (ks & 3) * 4 + kgrp;
    const short8 aF = *(const short8*)((const char*)&aT[tab][0] + arow * 256 + (slot_r ^ (arow & 7)) * 16);

    short8 bh[8], bl[8];
    const int fb = ks * 16;
    #pragma unroll
    for (int nt = 0; nt < 8; ++nt){
      bh[nt] = Bf[(size_t)(fb + nt * 2 + 0) * 64 + lane];
      bl[nt] = Bf[(size_t)(fb + nt * 2 + 1) * 64 + lane];
    }
    #pragma unroll
    for (int nt = 0; nt < 8; ++nt){
      mfma_bf16(acc[nt], aF, bh[nt]);
      mfma_bf16(acc[nt], aF, bl[nt]);
    }
  }

  const float alpha = *alpha_p;
  const int nodeQ = nodeBase + wv * 16 + kgrp * 4;

  if (out16){
    // layer 1: bf16 row-major h1 write
    #pragma unroll
    for (int nt = 0; nt < 8; ++nt){
      const int col = nt * 16 + mrow;
      const float bv = bias[col];
      #pragma unroll
      for (int j = 0; j < 4; ++j){
        const int onode = nodeQ + j;
        if (onode < n){
          float v = acc[nt][j] + bv;
          v = fmaxf(v, 0.f) + alpha * fminf(v, 0.f);
          out16[(size_t)onode * 128 + col] = bf16_rn(v);
        }
      }
    }
  } else {
    // layer 2: fused head dot: s = h2.u_l ; partial = h2.u_r + c
    float sdot[4] = {0,0,0,0}, tdot[4] = {0,0,0,0};
    #pragma unroll
    for (int nt = 0; nt < 8; ++nt){
      const int col = nt * 16 + mrow;
      const float bv = bias[col];
      const float ul = uvec[col];
      const float ur = uvec[128 + col];
      #pragma unroll
      for (int j = 0; j < 4; ++j){
        float v = acc[nt][j] + bv;
        v = fmaxf(v, 0.f) + alpha * fminf(v, 0.f);
        sdot[j] = fmaf(v, ul, sdot[j]);
        tdot[j] = fmaf(v, ur, tdot[j]);
      }
    }
    #pragma unroll
    for (int j = 0; j < 4; ++j){
      #pragma unroll
      for (int off = 1; off < 16; off <<= 1){
        sdot[j] += __shfl_xor(sdot[j], off);
        tdot[j] += __shfl_xor(tdot[j], off);
      }
    }
    if (mrow == 0){
      const float c = uvec[256];
      #pragma unroll
      for (int j = 0; j < 4; ++j){
        const int onode = nodeQ + j;
        if (onode < n){
          sbuf[onode] = sdot[j];
          pbuf[onode] = tdot[j] + c;
        }
      }
    }
  }
}

// ---------------- layer-3 fusion vector ----------------
__global__ void k_u(const float* __restrict__ w3l, const float* __restrict__ w3r,
                    const float* __restrict__ b3, const float* __restrict__ wp,
                    const float* __restrict__ bp, float* __restrict__ u){
  int k = threadIdx.x;
  float sl = 0.f, sr = 0.f;
  for (int o = 0; o < 64; ++o){
    float w = wp[o];
    sl = fmaf(w, w3l[o * 128 + k], sl);
    sr = fmaf(w, w3r[o * 128 + k], sr);
  }
  u[k] = sl; u[128 + k] = sr;
  if (k == 0){
    float c = bp[0];
    for (int o = 0; o < 64; ++o) c = fmaf(wp[o], b3[o], c);
    u[256] = c;
  }
}

__global__ __launch_bounds__(256) void k_final(const float* __restrict__ s, const float* __restrict__ partial,
                        const unsigned short* __restrict__ csr, const int* __restrict__ row_ptr,
                        const float* __restrict__ inv_cnt, float* __restrict__ out, int n){
  const int t = blockIdx.x * blockDim.x + threadIdx.x;
  const int node = t >> 2;
  const int sub = t & 3;
  if (node >= n) return;
  const int b = row_ptr[node], e = row_ptr[node + 1];
  float a0 = 0.f, a1 = 0.f;
  int j = b + sub;
  for (; j + 4 < e; j += 8){
    a0 += s[csr[j]];
    a1 += s[csr[j + 4]];
  }
  if (j < e) a0 += s[csr[j]];
  float acc = a0 + a1;
  acc += __shfl_down(acc, 1);
  acc += __shfl_down(acc, 2);
  if (sub == 0) out[node] = acc * inv_cnt[node] + partial[node];
}

// ---------------- launch ----------------
extern "C" void kernel_launch(void* const* d_in, const int* in_sizes, int n_in,
                              void* d_out, int out_size, void* d_ws, size_t ws_size,
                              hipStream_t stream){
  const float* x   = (const float*)d_in[0];
  const int*   ei  = (const int*)d_in[1];
  const float* w1l = (const float*)d_in[2];
  const float* w1r = (const float*)d_in[3];
  const float* b1  = (const float*)d_in[4];
  const float* w2l = (const float*)d_in[5];
  const float* w2r = (const float*)d_in[6];
  const float* b2  = (const float*)d_in[7];
  const float* w3l = (const float*)d_in[8];
  const float* w3r = (const float*)d_in[9];
  const float* b3  = (const float*)d_in[10];
  const float* ap  = (const float*)d_in[11];
  const float* wp  = (const float*)d_in[12];
  const float* bp  = (const float*)d_in[13];

  const int n = out_size;              // 50000 nodes
  const int E = in_sizes[1] / 2;       // 800000 edges
  const int* srcI = ei;
  const int* dstI = ei + E;

  const int ntiles = (E + 2047) / 2048;
  const int nb = (n + 255) >> 8;       // 196 buckets

  char* base = (char*)d_ws;
  size_t off = 0;
  auto take = [&](size_t bytes) -> char* {
    off = (off + 255) & ~(size_t)255;
    char* p = base + off;
    off += bytes;
    return p;
  };
  int*      blk_hist = (int*)   take((size_t)nb * ntiles * 4);
  int*      tot      = (int*)   take((size_t)nb * 4);
  int*      bbase    = (int*)   take(((size_t)nb + 1) * 4);
  unsigned* ebuf     = (unsigned*)take((size_t)E * 4);
  int*      rowp     = (int*)   take(((size_t)n + 1) * 4);
  float*    inv      = (float*) take((size_t)n * 4);
  unsigned short* csr = (unsigned short*)take((size_t)E * 2);
  unsigned short* B1b = (unsigned short*)take((size_t)n * 128 * 2);  // agg out, bf16
  unsigned short* xb  = (unsigned short*)take((size_t)n * 128 * 2);  // x bf16
  unsigned short* h1b = (unsigned short*)take((size_t)n * 128 * 2);  // h1 bf16
  float*    sbuf = (float*)take((size_t)n * 4);
  float*    pbuf = (float*)take((size_t)n * 4);
  float*    u    = (float*)take(257 * 4);
  short*    bfr  = (short*)take((size_t)128 * 512 * 2);
  (void)ws_size; (void)n_in;

  // CSR build: counting sort, no global atomics, coalesced writes
  k_bcount<<<ntiles, 256, 0, stream>>>(dstI, E, nb, ntiles, blk_hist);
  k_bscan <<<nb,     256, 0, stream>>>(blk_hist, nb, ntiles, tot);
  k_btot  <<<1,      256, 0, stream>>>(tot, nb, bbase);
  k_bscat <<<ntiles, 256, 0, stream>>>(srcI, dstI, E, nb, ntiles, blk_hist, bbase, ebuf);
  k_csrfin<<<nb,     256, 0, stream>>>(ebuf, bbase, n, E, nb, rowp, inv, csr);

  // bf16 feature table
  k_cvt<<<(n * 128 / 4 + 255) / 256, 256, 0, stream>>>(x, xb, n * 128);

  const int aggGrid  = (n * 64 + 255) / 256;
  const int gemmGrid = (n + 63) / 64;

  // layer 1: h1 = prelu([agg(x)|x] @ W1 + b1)  -> bf16
  k_aggb     <<<aggGrid, 256, 0, stream>>>(xb, csr, rowp, inv, B1b, n);
  k_wcs      <<<128, 256, 0, stream>>>(w1l, w1r, bfr);
  k_gemm_mfma<<<gemmGrid, 256, 0, stream>>>(B1b, xb, bfr, b1, ap, h1b,
                                            (const float*)nullptr, (float*)nullptr, (float*)nullptr, n);

  // layer 2: fused h2 GEMM + head dot -> sbuf/pbuf (h2 never materialized)
  k_u        <<<1, 128, 0, stream>>>(w3l, w3r, b3, wp, bp, u);
  k_aggb     <<<aggGrid, 256, 0, stream>>>(h1b, csr, rowp, inv, B1b, n);
  k_wcs      <<<128, 256, 0, stream>>>(w2l, w2r, bfr);
  k_gemm_mfma<<<gemmGrid, 256, 0, stream>>>(B1b, h1b, bfr, b2, ap, (unsigned short*)nullptr,
                                            u, sbuf, pbuf, n);

  // final: level = mean(s) + partial
  k_final<<<(n * 4 + 255) / 256, 256, 0, stream>>>(sbuf, pbuf, csr, rowp, inv, (float*)d_out, n);
}

// Round 12
// 155.994 us; speedup vs baseline: 1.9892x; 1.0486x over previous
//
#include <hip/hip_runtime.h>
#include <cstdint>
#include <cstddef>

typedef float f32x4 __attribute__((ext_vector_type(4)));
typedef short short8 __attribute__((ext_vector_type(8)));
typedef __bf16 bf16x8 __attribute__((ext_vector_type(8)));

__device__ __forceinline__ void mfma_bf16(f32x4& d, short8 a, short8 b){
  d = __builtin_amdgcn_mfma_f32_16x16x32_bf16(
        __builtin_bit_cast(bf16x8, a), __builtin_bit_cast(bf16x8, b), d, 0, 0, 0);
}

__device__ __forceinline__ unsigned short bf16_rn(float f){
  unsigned u = __float_as_uint(f);
  unsigned r = (u + 0x7FFF + ((u >> 16) & 1)) >> 16;
  return (unsigned short)r;
}

// 256-thread exclusive block scan (4 waves).
__device__ __forceinline__ int blockScan256Excl(int v, int* wsum){
  const int lane = threadIdx.x & 63, wv = threadIdx.x >> 6;
  int x = v;
  #pragma unroll
  for (int off = 1; off < 64; off <<= 1){
    int y = __shfl_up(x, off);
    if (lane >= off) x += y;
  }
  if (lane == 63) wsum[wv] = x;
  __syncthreads();
  int woff = 0;
  #pragma unroll
  for (int w = 0; w < 4; ++w) woff += (w < wv) ? wsum[w] : 0;
  return woff + x - v;
}

// ================= CSR build: two-level counting sort (no global atomics) =================
__global__ __launch_bounds__(256) void k_bcount(const int* __restrict__ dst, int E, int nb, int ntiles,
                                                int* __restrict__ blk_hist){
  __shared__ int h[256];
  const int tile = blockIdx.x;
  h[threadIdx.x] = 0;
  __syncthreads();
  const int base = tile * 2048;
  const int end = min(base + 2048, E);
  for (int i = base + threadIdx.x; i < end; i += 256)
    atomicAdd(&h[dst[i] >> 8], 1);
  __syncthreads();
  const int b = threadIdx.x;
  if (b < nb) blk_hist[(size_t)b * ntiles + tile] = h[b];
}

__global__ __launch_bounds__(256) void k_bscan(int* __restrict__ blk_hist, int nb, int ntiles,
                                               int* __restrict__ tot){
  __shared__ int wsum[4];
  __shared__ int carry;
  const int b = blockIdx.x;
  int* row = blk_hist + (size_t)b * ntiles;
  if (threadIdx.x == 0) carry = 0;
  __syncthreads();
  const int lane = threadIdx.x & 63, wv = threadIdx.x >> 6;
  for (int base = 0; base < ntiles; base += 256){
    const int i = base + threadIdx.x;
    const int v = (i < ntiles) ? row[i] : 0;
    int x = v;
    #pragma unroll
    for (int off = 1; off < 64; off <<= 1){
      int y = __shfl_up(x, off);
      if (lane >= off) x += y;
    }
    if (lane == 63) wsum[wv] = x;
    __syncthreads();
    int woff = 0;
    #pragma unroll
    for (int w = 0; w < 4; ++w) woff += (w < wv) ? wsum[w] : 0;
    const int incl = carry + woff + x;
    if (i < ntiles) row[i] = incl - v;
    __syncthreads();
    if (threadIdx.x == 255) carry = incl;
    __syncthreads();
  }
  if (threadIdx.x == 0) tot[b] = carry;
}

__global__ __launch_bounds__(256) void k_btot(const int* __restrict__ tot, int nb,
                                              int* __restrict__ bucket_base){
  __shared__ int wsum[4];
  const int t = threadIdx.x;
  const int v = (t < nb) ? tot[t] : 0;
  const int e = blockScan256Excl(v, wsum);
  if (t <= nb) bucket_base[t] = e;
}

__global__ __launch_bounds__(256) void k_bscat(const int* __restrict__ src, const int* __restrict__ dst,
                                               int E, int nb, int ntiles,
                                               const int* __restrict__ blk_off,
                                               const int* __restrict__ bucket_base,
                                               unsigned* __restrict__ ebuf){
  __shared__ int cnt[256];
  __shared__ int lofs[256];
  __shared__ int gbase[256];
  __shared__ unsigned sorted[2048];
  __shared__ unsigned char sb[2048];
  __shared__ int wsum[4];
  const int tile = blockIdx.x;
  cnt[threadIdx.x] = 0;
  __syncthreads();
  const int base = tile * 2048;
  const int end = min(base + 2048, E);
  const int m = end - base;

  int rank_[8]; int b_[8]; unsigned v_[8];
  #pragma unroll
  for (int k = 0; k < 8; ++k){
    const int j = threadIdx.x + k * 256;
    if (base + j < end){
      const int d = dst[base + j];
      const int s = src[base + j];
      const int b = d >> 8;
      b_[k] = b;
      v_[k] = ((unsigned)(d & 255) << 16) | (unsigned)s;
      rank_[k] = atomicAdd(&cnt[b], 1);
    } else b_[k] = -1;
  }
  __syncthreads();
  const int ex = blockScan256Excl(cnt[threadIdx.x], wsum);
  lofs[threadIdx.x] = ex;
  if (threadIdx.x < nb)
    gbase[threadIdx.x] = bucket_base[threadIdx.x] + blk_off[(size_t)threadIdx.x * ntiles + tile];
  __syncthreads();
  #pragma unroll
  for (int k = 0; k < 8; ++k){
    if (b_[k] >= 0){
      const int p = lofs[b_[k]] + rank_[k];
      sorted[p] = v_[k];
      sb[p] = (unsigned char)b_[k];
    }
  }
  __syncthreads();
  for (int j = threadIdx.x; j < m; j += 256){
    const int b = sb[j];
    ebuf[gbase[b] + (j - lofs[b])] = sorted[j];
  }
}

__global__ __launch_bounds__(256) void k_csrfin(const unsigned* __restrict__ ebuf,
                                                const int* __restrict__ bucket_base,
                                                int n, int E, int nb,
                                                int* __restrict__ row_ptr,
                                                float* __restrict__ inv,
                                                unsigned short* __restrict__ csr){
  __shared__ int hist[256], excl[256], cursor[256];
  __shared__ int wsum[4];
  __shared__ unsigned vals[8192];
  __shared__ unsigned short sorted[8192];
  const int b = blockIdx.x;
  const int ebase = bucket_base[b];
  const int ecnt = bucket_base[b + 1] - ebase;
  const int t = threadIdx.x;
  hist[t] = 0;
  __syncthreads();
  for (int j = t; j < ecnt; j += 256){
    const unsigned v = ebuf[ebase + j];
    vals[j] = v;
    atomicAdd(&hist[v >> 16], 1);
  }
  __syncthreads();
  const int ex = blockScan256Excl(hist[t], wsum);
  excl[t] = ex;
  cursor[t] = ex;
  const int node = b * 256 + t;
  if (node < n){
    row_ptr[node] = ebase + ex;
    const int c = hist[t];
    inv[node] = 1.0f / (float)(c > 0 ? c : 1);
  }
  if (b == nb - 1 && t == 0) row_ptr[n] = E;
  __syncthreads();
  for (int j = t; j < ecnt; j += 256){
    const unsigned v = vals[j];
    const int pos = atomicAdd(&cursor[v >> 16], 1);
    sorted[pos] = (unsigned short)(v & 0xFFFFu);
  }
  __syncthreads();
  for (int j = t; j < ecnt; j += 256)
    csr[ebase + j] = sorted[j];
}

// ================= fused prep: x->bf16 cvt | W1 pack | W2 pack | u vector =================
__device__ __forceinline__ void wcs_body(const float* __restrict__ wl, const float* __restrict__ wr,
                                         short* __restrict__ bfr, int id){
  if (id >= 128 * 256) return;
  int c = id >> 8, k = id & 255;
  float w = (k < 128) ? wl[c * 128 + k] : wr[c * 128 + (k - 128)];
  unsigned short h = bf16_rn(w);
  float hf = __uint_as_float((unsigned)h << 16);
  unsigned short l = bf16_rn(w - hf);
  const int nt = c >> 4, mrow = c & 15;
  const int ks = k >> 5, kgrp = (k >> 3) & 3, j = k & 7;
  const int lane = kgrp * 16 + mrow;
  const size_t fbase = (size_t)((ks * 8 + nt) * 2) * 512 + lane * 8 + j;
  bfr[fbase] = (short)h;
  bfr[fbase + 512] = (short)l;
}

__global__ __launch_bounds__(256) void k_prep(const float* __restrict__ x,
                                              unsigned short* __restrict__ xb, int n,
                                              const float* __restrict__ w1l, const float* __restrict__ w1r,
                                              short* __restrict__ bfr1,
                                              const float* __restrict__ w2l, const float* __restrict__ w2r,
                                              short* __restrict__ bfr2,
                                              const float* __restrict__ w3l, const float* __restrict__ w3r,
                                              const float* __restrict__ b3,
                                              const float* __restrict__ wp, const float* __restrict__ bp,
                                              float* __restrict__ u){
  const int nbcvt = (n * 128 / 4 + 255) / 256;
  const int b = blockIdx.x;
  if (b < nbcvt){
    const int i = (b * 256 + threadIdx.x) * 4;
    if (i < n * 128){
      const float4 v = *(const float4*)&x[i];
      ushort2 a, c;
      a.x = bf16_rn(v.x); a.y = bf16_rn(v.y);
      c.x = bf16_rn(v.z); c.y = bf16_rn(v.w);
      *(ushort2*)&xb[i] = a;
      *(ushort2*)&xb[i + 2] = c;
    }
  } else if (b < nbcvt + 128){
    wcs_body(w1l, w1r, bfr1, (b - nbcvt) * 256 + threadIdx.x);
  } else if (b < nbcvt + 256){
    wcs_body(w2l, w2r, bfr2, (b - nbcvt - 128) * 256 + threadIdx.x);
  } else {
    const int k = threadIdx.x;
    if (k < 128){
      float sl = 0.f, sr = 0.f;
      for (int o = 0; o < 64; ++o){
        float w = wp[o];
        sl = fmaf(w, w3l[o * 128 + k], sl);
        sr = fmaf(w, w3r[o * 128 + k], sr);
      }
      u[k] = sl; u[128 + k] = sr;
      if (k == 0){
        float c = bp[0];
        for (int o = 0; o < 64; ++o) c = fmaf(wp[o], b3[o], c);
        u[256] = c;
      }
    }
  }
}

// ---------------- mean aggregation: bf16 gather, fp32 accumulate, bf16 out ----------------
// one wave per node; lane covers one uint (2 bf16) per row; unroll-16 MLP,
// wave-uniform CSR window scalarized via readfirstlane.
__global__ __launch_bounds__(256) void k_aggb(const unsigned short* __restrict__ featb,
                                              const unsigned short* __restrict__ csr,
                                              const int* __restrict__ row_ptr,
                                              const float* __restrict__ inv_cnt,
                                              unsigned short* __restrict__ outb, int n){
  const int lane = threadIdx.x & 63;
  const int node = (blockIdx.x * blockDim.x + threadIdx.x) >> 6;
  if (node >= n) return;
  const int beg = __builtin_amdgcn_readfirstlane(row_ptr[node]);
  const int end = __builtin_amdgcn_readfirstlane(row_ptr[node + 1]);
  const unsigned* __restrict__ fb = (const unsigned*)featb;   // [node][64]

  float axs[8] = {0,0,0,0,0,0,0,0};
  float ays[8] = {0,0,0,0,0,0,0,0};

  int j = beg;
  for (; j + 16 <= end; j += 16){
    unsigned uu[16];
    #pragma unroll
    for (int q = 0; q < 16; ++q) uu[q] = fb[(size_t)csr[j + q] * 64 + lane];
    #pragma unroll
    for (int q = 0; q < 16; ++q){
      axs[q & 7] += __uint_as_float(uu[q] << 16);
      ays[q & 7] += __uint_as_float(uu[q] & 0xFFFF0000u);
    }
  }
  if (j + 8 <= end){
    unsigned uu[8];
    #pragma unroll
    for (int q = 0; q < 8; ++q) uu[q] = fb[(size_t)csr[j + q] * 64 + lane];
    #pragma unroll
    for (int q = 0; q < 8; ++q){
      axs[q] += __uint_as_float(uu[q] << 16);
      ays[q] += __uint_as_float(uu[q] & 0xFFFF0000u);
    }
    j += 8;
  }
  if (j + 4 <= end){
    unsigned uu[4];
    #pragma unroll
    for (int q = 0; q < 4; ++q) uu[q] = fb[(size_t)csr[j + q] * 64 + lane];
    #pragma unroll
    for (int q = 0; q < 4; ++q){
      axs[q] += __uint_as_float(uu[q] << 16);
      ays[q] += __uint_as_float(uu[q] & 0xFFFF0000u);
    }
    j += 4;
  }
  for (; j < end; ++j){
    const unsigned u = fb[(size_t)csr[j] * 64 + lane];
    axs[4] += __uint_as_float(u << 16);
    ays[4] += __uint_as_float(u & 0xFFFF0000u);
  }

  const float ic = inv_cnt[node];
  const float ox = (((axs[0] + axs[1]) + (axs[2] + axs[3])) + ((axs[4] + axs[5]) + (axs[6] + axs[7]))) * ic;
  const float oy = (((ays[0] + ays[1]) + (ays[2] + ays[3])) + ((ays[4] + ays[5]) + (ays[6] + ays[7]))) * ic;
  const unsigned packed = (unsigned)bf16_rn(ox) | ((unsigned)bf16_rn(oy) << 16);
  ((unsigned*)outb)[(size_t)node * 64 + lane] = packed;
}

// ---------------- MFMA GEMM: prelu([A0|A1] @ W^T + b) ----------------
// A0,A1 bf16 row-major [n][128]; A staged in LDS (XOR-swizzled); W split hi/lo.
// Layer1 (out16 != null): write h1 bf16 row-major.
// Layer2 (uvec != null): fused head dot -> sbuf/pbuf (h2 never materialized).
__global__ __launch_bounds__(256) void k_gemm_mfma(const unsigned short* __restrict__ A0b,
                                                   const unsigned short* __restrict__ A1b,
                                                   const short* __restrict__ bfr,
                                                   const float* __restrict__ bias,
                                                   const float* __restrict__ alpha_p,
                                                   unsigned short* __restrict__ out16,  // or null
                                                   const float* __restrict__ uvec,      // or null
                                                   float* __restrict__ sbuf,
                                                   float* __restrict__ pbuf,
                                                   int n){
  __shared__ short aT[2][64 * 128];   // 2 tables x 64 rows x 256B, XOR-swizzled
  const int t = threadIdx.x;
  const int lane = t & 63;
  const int wv = t >> 6;
  const int nodeBase = blockIdx.x * 64;

  #pragma unroll
  for (int tab = 0; tab < 2; ++tab){
    const unsigned short* __restrict__ src = tab ? A1b : A0b;
    #pragma unroll
    for (int it = 0; it < 4; ++it){
      const int chunk = it * 256 + t;
      const int row = chunk >> 4;
      const int slot = chunk & 15;
      int gr = nodeBase + row; if (gr > n - 1) gr = n - 1;
      const uint4 v = *(const uint4*)&src[(size_t)gr * 128 + slot * 8];
      const int sslot = slot ^ (row & 7);
      *(uint4*)((char*)&aT[tab][0] + row * 256 + sslot * 16) = v;
    }
  }
  __syncthreads();

  const short8* __restrict__ Bf = (const short8*)bfr;
  const int mrow = lane & 15;
  const int kgrp = lane >> 4;
  const int arow = wv * 16 + mrow;

  f32x4 acc[8];
  #pragma unroll
  for (int i = 0; i < 8; ++i) acc[i] = (f32x4){0.f, 0.f, 0.f, 0.f};

  #pragma unroll
  for (int ks = 0; ks < 8; ++ks){
    const int tab = ks >> 2;
    const int slot_r = (ks & 3) * 4 + kgrp;
    const short8 aF = *(const short8*)((const char*)&aT[tab][0] + arow * 256 + (slot_r ^ (arow & 7)) * 16);

    short8 bh[8], bl[8];
    const int fb = ks * 16;
    #pragma unroll
    for (int nt = 0; nt < 8; ++nt){
      bh[nt] = Bf[(size_t)(fb + nt * 2 + 0) * 64 + lane];
      bl[nt] = Bf[(size_t)(fb + nt * 2 + 1) * 64 + lane];
    }
    #pragma unroll
    for (int nt = 0; nt < 8; ++nt){
      mfma_bf16(acc[nt], aF, bh[nt]);
      mfma_bf16(acc[nt], aF, bl[nt]);
    }
  }

  const float alpha = *alpha_p;
  const int nodeQ = nodeBase + wv * 16 + kgrp * 4;

  if (out16){
    #pragma unroll
    for (int nt = 0; nt < 8; ++nt){
      const int col = nt * 16 + mrow;
      const float bv = bias[col];
      #pragma unroll
      for (int j = 0; j < 4; ++j){
        const int onode = nodeQ + j;
        if (onode < n){
          float v = acc[nt][j] + bv;
          v = fmaxf(v, 0.f) + alpha * fminf(v, 0.f);
          out16[(size_t)onode * 128 + col] = bf16_rn(v);
        }
      }
    }
  } else {
    float sdot[4] = {0,0,0,0}, tdot[4] = {0,0,0,0};
    #pragma unroll
    for (int nt = 0; nt < 8; ++nt){
      const int col = nt * 16 + mrow;
      const float bv = bias[col];
      const float ul = uvec[col];
      const float ur = uvec[128 + col];
      #pragma unroll
      for (int j = 0; j < 4; ++j){
        float v = acc[nt][j] + bv;
        v = fmaxf(v, 0.f) + alpha * fminf(v, 0.f);
        sdot[j] = fmaf(v, ul, sdot[j]);
        tdot[j] = fmaf(v, ur, tdot[j]);
      }
    }
    #pragma unroll
    for (int j = 0; j < 4; ++j){
      #pragma unroll
      for (int off = 1; off < 16; off <<= 1){
        sdot[j] += __shfl_xor(sdot[j], off);
        tdot[j] += __shfl_xor(tdot[j], off);
      }
    }
    if (mrow == 0){
      const float c = uvec[256];
      #pragma unroll
      for (int j = 0; j < 4; ++j){
        const int onode = nodeQ + j;
        if (onode < n){
          sbuf[onode] = sdot[j];
          pbuf[onode] = tdot[j] + c;
        }
      }
    }
  }
}

__global__ __launch_bounds__(256) void k_final(const float* __restrict__ s, const float* __restrict__ partial,
                        const unsigned short* __restrict__ csr, const int* __restrict__ row_ptr,
                        const float* __restrict__ inv_cnt, float* __restrict__ out, int n){
  const int t = blockIdx.x * blockDim.x + threadIdx.x;
  const int node = t >> 2;
  const int sub = t & 3;
  if (node >= n) return;
  const int b = row_ptr[node], e = row_ptr[node + 1];
  float a0 = 0.f, a1 = 0.f;
  int j = b + sub;
  for (; j + 4 < e; j += 8){
    a0 += s[csr[j]];
    a1 += s[csr[j + 4]];
  }
  if (j < e) a0 += s[csr[j]];
  float acc = a0 + a1;
  acc += __shfl_down(acc, 1);
  acc += __shfl_down(acc, 2);
  if (sub == 0) out[node] = acc * inv_cnt[node] + partial[node];
}

// ---------------- launch ----------------
extern "C" void kernel_launch(void* const* d_in, const int* in_sizes, int n_in,
                              void* d_out, int out_size, void* d_ws, size_t ws_size,
                              hipStream_t stream){
  const float* x   = (const float*)d_in[0];
  const int*   ei  = (const int*)d_in[1];
  const float* w1l = (const float*)d_in[2];
  const float* w1r = (const float*)d_in[3];
  const float* b1  = (const float*)d_in[4];
  const float* w2l = (const float*)d_in[5];
  const float* w2r = (const float*)d_in[6];
  const float* b2  = (const float*)d_in[7];
  const float* w3l = (const float*)d_in[8];
  const float* w3r = (const float*)d_in[9];
  const float* b3  = (const float*)d_in[10];
  const float* ap  = (const float*)d_in[11];
  const float* wp  = (const float*)d_in[12];
  const float* bp  = (const float*)d_in[13];

  const int n = out_size;              // 50000 nodes
  const int E = in_sizes[1] / 2;       // 800000 edges
  const int* srcI = ei;
  const int* dstI = ei + E;

  const int ntiles = (E + 2047) / 2048;
  const int nb = (n + 255) >> 8;       // 196 buckets

  char* base = (char*)d_ws;
  size_t off = 0;
  auto take = [&](size_t bytes) -> char* {
    off = (off + 255) & ~(size_t)255;
    char* p = base + off;
    off += bytes;
    return p;
  };
  int*      blk_hist = (int*)   take((size_t)nb * ntiles * 4);
  int*      tot      = (int*)   take((size_t)nb * 4);
  int*      bbase    = (int*)   take(((size_t)nb + 1) * 4);
  unsigned* ebuf     = (unsigned*)take((size_t)E * 4);
  int*      rowp     = (int*)   take(((size_t)n + 1) * 4);
  float*    inv      = (float*) take((size_t)n * 4);
  unsigned short* csr = (unsigned short*)take((size_t)E * 2);
  unsigned short* B1b = (unsigned short*)take((size_t)n * 128 * 2);  // agg out, bf16
  unsigned short* xb  = (unsigned short*)take((size_t)n * 128 * 2);  // x bf16
  unsigned short* h1b = (unsigned short*)take((size_t)n * 128 * 2);  // h1 bf16
  float*    sbuf = (float*)take((size_t)n * 4);
  float*    pbuf = (float*)take((size_t)n * 4);
  float*    u    = (float*)take(257 * 4);
  short*    bfr1 = (short*)take((size_t)128 * 512 * 2);
  short*    bfr2 = (short*)take((size_t)128 * 512 * 2);
  (void)ws_size; (void)n_in;

  // CSR build: counting sort, no global atomics, coalesced writes
  k_bcount<<<ntiles, 256, 0, stream>>>(dstI, E, nb, ntiles, blk_hist);
  k_bscan <<<nb,     256, 0, stream>>>(blk_hist, nb, ntiles, tot);
  k_btot  <<<1,      256, 0, stream>>>(tot, nb, bbase);
  k_bscat <<<ntiles, 256, 0, stream>>>(srcI, dstI, E, nb, ntiles, blk_hist, bbase, ebuf);
  k_csrfin<<<nb,     256, 0, stream>>>(ebuf, bbase, n, E, nb, rowp, inv, csr);

  // fused prep: x->bf16 | W1 pack | W2 pack | u vector
  const int nbcvt = (n * 128 / 4 + 255) / 256;
  k_prep<<<nbcvt + 257, 256, 0, stream>>>(x, xb, n, w1l, w1r, bfr1, w2l, w2r, bfr2,
                                          w3l, w3r, b3, wp, bp, u);

  const int aggGrid  = (n * 64 + 255) / 256;
  const int gemmGrid = (n + 63) / 64;

  // layer 1: h1 = prelu([agg(x)|x] @ W1 + b1)  -> bf16
  k_aggb     <<<aggGrid, 256, 0, stream>>>(xb, csr, rowp, inv, B1b, n);
  k_gemm_mfma<<<gemmGrid, 256, 0, stream>>>(B1b, xb, bfr1, b1, ap, h1b,
                                            (const float*)nullptr, (float*)nullptr, (float*)nullptr, n);

  // layer 2: fused h2 GEMM + head dot -> sbuf/pbuf (h2 never materialized)
  k_aggb     <<<aggGrid, 256, 0, stream>>>(h1b, csr, rowp, inv, B1b, n);
  k_gemm_mfma<<<gemmGrid, 256, 0, stream>>>(B1b, h1b, bfr2, b2, ap, (unsigned short*)nullptr,
                                            u, sbuf, pbuf, n);

  // final: level = mean(s) + partial
  k_final<<<(n * 4 + 255) / 256, 256, 0, stream>>>(sbuf, pbuf, csr, rowp, inv, (float*)d_out, n);
}